// Round 1
// baseline (1563.128 us; speedup 1.0000x reference)
//
#include <hip/hip_runtime.h>
#include <math.h>

#define DD 128

// ---------- degree / CSR build ----------

__global__ __launch_bounds__(256) void k_deg_count(const int* __restrict__ col,
                                                   int* __restrict__ deg, int E) {
  int e = blockIdx.x * 256 + threadIdx.x;
  if (e < E) atomicAdd(&deg[col[e]], 1);
}

__global__ __launch_bounds__(256) void k_dinv(const int* __restrict__ deg,
                                              float* __restrict__ dinv, int n) {
  int i = blockIdx.x * 256 + threadIdx.x;
  if (i < n) dinv[i] = rsqrtf(1.0f + (float)deg[i]);
}

__global__ __launch_bounds__(256) void k_chunk_sum(const int* __restrict__ deg,
                                                   int* __restrict__ csum, int n) {
  __shared__ int s[256];
  int t = threadIdx.x, i = blockIdx.x * 256 + t;
  s[t] = (i < n) ? deg[i] : 0;
  __syncthreads();
  for (int o = 128; o > 0; o >>= 1) {
    if (t < o) s[t] += s[t + o];
    __syncthreads();
  }
  if (t == 0) csum[blockIdx.x] = s[0];
}

__global__ void k_scan_serial(const int* __restrict__ csum, int* __restrict__ cbase, int nch) {
  if (threadIdx.x == 0 && blockIdx.x == 0) {
    int run = 0;
    for (int i = 0; i < nch; i++) { cbase[i] = run; run += csum[i]; }
    cbase[nch] = run;
  }
}

__global__ __launch_bounds__(256) void k_chunk_scan(const int* __restrict__ deg,
                                                    const int* __restrict__ cbase,
                                                    int* __restrict__ off, int n) {
  __shared__ int s[256];
  int t = threadIdx.x, i = blockIdx.x * 256 + t;
  int v = (i < n) ? deg[i] : 0;
  s[t] = v;
  __syncthreads();
  for (int o = 1; o < 256; o <<= 1) {
    int add = (t >= o) ? s[t - o] : 0;
    __syncthreads();
    s[t] += add;
    __syncthreads();
  }
  int incl = s[t];
  int base = cbase[blockIdx.x];
  if (i < n) off[i] = base + (incl - v);
  if (i == n - 1) off[n] = base + incl;
}

__global__ __launch_bounds__(256) void k_copy_i32(const int* __restrict__ src,
                                                  int* __restrict__ dst, int n) {
  int i = blockIdx.x * 256 + threadIdx.x;
  if (i < n) dst[i] = src[i];
}

__global__ __launch_bounds__(256) void k_bucket(const int* __restrict__ row,
                                                const int* __restrict__ col,
                                                int* __restrict__ cursor,
                                                int* __restrict__ srt, int E) {
  int e = blockIdx.x * 256 + threadIdx.x;
  if (e < E) {
    int d = col[e];
    int pos = atomicAdd(&cursor[d], 1);
    srt[pos] = row[e];
  }
}

// ---------- GEMM: Y[n,128] = X[n,128] @ W[128,128] ----------
// 32 rows/block, 256 threads, each thread 4 rows x 4 cols.
// W staged in LDS in two k-halves (keeps static LDS at 48KB -> 3 blocks/CU).

__global__ __launch_bounds__(256, 2) void k_gemm(const float* __restrict__ X,
                                                 const float* __restrict__ W,
                                                 float* __restrict__ Y, int nrows) {
  __shared__ float Ws[64 * 128];  // 32KB, one k-half
  __shared__ float Xs[32 * 128];  // 16KB
  int tid = threadIdx.x;
  int row0 = blockIdx.x * 32;

  // load 32 rows of X (1024 float4, 4 per thread)
  for (int i = tid; i < 1024; i += 256) {
    int r = i >> 5, c = i & 31;
    int gr = row0 + r;
    float4 v = make_float4(0.f, 0.f, 0.f, 0.f);
    if (gr < nrows) v = ((const float4*)(X + (size_t)gr * DD))[c];
    ((float4*)Xs)[i] = v;
  }

  int cg = (tid & 31) * 4;        // 4 output cols
  int rbase = (tid >> 5) * 4;     // 4 output rows
  float acc[4][4];
#pragma unroll
  for (int a = 0; a < 4; a++)
#pragma unroll
    for (int b = 0; b < 4; b++) acc[a][b] = 0.f;

  for (int half = 0; half < 2; half++) {
    __syncthreads();  // protect Ws reuse + Xs ready on first pass
    // load this k-half of W: 64*128 floats = 2048 float4, 8/thread
    for (int i = tid; i < 2048; i += 256)
      ((float4*)Ws)[i] = ((const float4*)(W + half * 64 * DD))[i];
    __syncthreads();
    int kbase = half * 64;
#pragma unroll 4
    for (int k = 0; k < 64; k += 4) {
      float4 xv[4];
#pragma unroll
      for (int rr = 0; rr < 4; rr++)
        xv[rr] = *(const float4*)&Xs[(rbase + rr) * DD + kbase + k];
#pragma unroll
      for (int kk = 0; kk < 4; kk++) {
        float4 wv = *(const float4*)&Ws[(k + kk) * DD + cg];
#pragma unroll
        for (int rr = 0; rr < 4; rr++) {
          float x = (kk == 0) ? xv[rr].x : (kk == 1) ? xv[rr].y : (kk == 2) ? xv[rr].z : xv[rr].w;
          acc[rr][0] += x * wv.x;
          acc[rr][1] += x * wv.y;
          acc[rr][2] += x * wv.z;
          acc[rr][3] += x * wv.w;
        }
      }
    }
  }

#pragma unroll
  for (int rr = 0; rr < 4; rr++) {
    int gr = row0 + rbase + rr;
    if (gr < nrows) {
      float4 o = make_float4(acc[rr][0], acc[rr][1], acc[rr][2], acc[rr][3]);
      *(float4*)(Y + (size_t)gr * DD + cg) = o;
    }
  }
}

// ---------- aggregate: out[n,d] = f( dinv[n]*sum_e dinv[src]*xw[src,d]
//                                     + dinv[n]^2*xw[n,d] + bias[d] ) ----------
// 2 nodes per block, 128 threads per node (one per feature).

__global__ __launch_bounds__(256) void k_agg(const float* __restrict__ xw,
                                             const int* __restrict__ srt,
                                             const int* __restrict__ off,
                                             const float* __restrict__ dinv,
                                             const float* __restrict__ bias,
                                             float* __restrict__ out, int n, int relu) {
  int node = blockIdx.x * 2 + (threadIdx.x >> 7);
  int d = threadIdx.x & 127;
  if (node >= n) return;
  int beg = off[node], end = off[node + 1];
  float acc0 = 0.f, acc1 = 0.f;
  int j = beg;
  for (; j + 2 <= end; j += 2) {
    int s0 = srt[j], s1 = srt[j + 1];
    acc0 += dinv[s0] * xw[(size_t)s0 * DD + d];
    acc1 += dinv[s1] * xw[(size_t)s1 * DD + d];
  }
  if (j < end) {
    int s0 = srt[j];
    acc0 += dinv[s0] * xw[(size_t)s0 * DD + d];
  }
  float di = dinv[node];
  float self = xw[(size_t)node * DD + d];
  float v = di * (acc0 + acc1) + di * di * self + bias[d];
  if (relu) v = fmaxf(v, 0.f);
  out[(size_t)node * DD + d] = v;
}

// ---------- column logsumexp over node dim ----------

__device__ inline unsigned f2ord(float f) {
  unsigned b = __float_as_uint(f);
  return b ^ ((b >> 31) ? 0xFFFFFFFFu : 0x80000000u);
}
__device__ inline float ord2f(unsigned t) {
  unsigned b = t ^ ((t >> 31) ? 0x80000000u : 0xFFFFFFFFu);
  return __uint_as_float(b);
}

__global__ __launch_bounds__(256) void k_colmax(const float* __restrict__ h, int n,
                                                unsigned* __restrict__ Mu) {
  __shared__ float red[2][128];
  int d = threadIdx.x & 127, sub = threadIdx.x >> 7;
  float m = -3.4e38f;
  for (int r = blockIdx.x * 2 + sub; r < n; r += gridDim.x * 2)
    m = fmaxf(m, h[(size_t)r * DD + d]);
  red[sub][d] = m;
  __syncthreads();
  if (sub == 0) atomicMax(&Mu[d], f2ord(fmaxf(red[0][d], red[1][d])));
}

__global__ __launch_bounds__(256) void k_colsum(const float* __restrict__ h, int n,
                                                const unsigned* __restrict__ Mu,
                                                float* __restrict__ S) {
  __shared__ float red[2][128];
  int d = threadIdx.x & 127, sub = threadIdx.x >> 7;
  float M = ord2f(Mu[d]);
  float s = 0.f;
  for (int r = blockIdx.x * 2 + sub; r < n; r += gridDim.x * 2)
    s += expf(h[(size_t)r * DD + d] - M);
  red[sub][d] = s;
  __syncthreads();
  if (sub == 0) atomicAdd(&S[d], red[0][d] + red[1][d]);
}

__global__ void k_lse(const unsigned* __restrict__ Mu, const float* __restrict__ S,
                      float* __restrict__ L) {
  int d = threadIdx.x;
  L[d] = ord2f(Mu[d]) + logf(S[d]);
}

// ---------- final: out[b,n,d] = h2[n,d] - L[d], replicated over b ----------

__global__ __launch_bounds__(256) void k_final(const float* __restrict__ h,
                                               const float* __restrict__ L,
                                               float* __restrict__ out, int n, int B) {
  int idx = blockIdx.x * 256 + threadIdx.x;
  int nd4 = n * 32;
  if (idx >= nd4) return;
  int c4 = idx & 31;
  float4 hv = ((const float4*)h)[idx];
  float4 lv = ((const float4*)L)[c4];
  float4 r = make_float4(hv.x - lv.x, hv.y - lv.y, hv.z - lv.z, hv.w - lv.w);
  float4* o = (float4*)out;
  for (int b = 0; b < B; b++) o[(size_t)idx + (size_t)b * nd4] = r;
}

// ---------- launch ----------

extern "C" void kernel_launch(void* const* d_in, const int* in_sizes, int n_in,
                              void* d_out, int out_size, void* d_ws, size_t ws_size,
                              hipStream_t stream) {
  const float* x  = (const float*)d_in[0];
  const int*   ei = (const int*)d_in[1];
  const float* W1 = (const float*)d_in[3];
  const float* b1 = (const float*)d_in[4];
  const float* W2 = (const float*)d_in[5];
  const float* b2 = (const float*)d_in[6];
  // question_embeddings / Wq / bq cancel in log_softmax over the node axis.

  int n = in_sizes[0] / DD;
  int E = in_sizes[1] / 2;
  int B = out_size / (n * DD);
  const int* row = ei;
  const int* col = ei + E;

  float* out = (float*)d_out;
  size_t nd = (size_t)n * DD;
  // d_out used as scratch: slab0 = xw ping, slab1 = h pong (read in-place by
  // k_final), slab2 = sorted sources, slab3 = small arrays. All scratch is dead
  // before k_final rewrites every output element.
  float* bufA = out;
  float* bufB = out + nd;
  int* srt = (int*)(out + 2 * nd);
  char* sm = (char*)(out + 3 * nd);
  int* deg = (int*)sm;        sm += sizeof(int) * n;
  float* dinv = (float*)sm;   sm += sizeof(float) * n;
  int* off = (int*)sm;        sm += sizeof(int) * (n + 1);
  int* cursor = (int*)sm;     sm += sizeof(int) * n;
  int nch = (n + 255) / 256;
  int* csum = (int*)sm;       sm += sizeof(int) * nch;
  int* cbase = (int*)sm;      sm += sizeof(int) * (nch + 1);

  unsigned* Mu = (unsigned*)d_ws;       // 128 u32
  float* S = (float*)d_ws + 128;        // 128 f32
  float* L = (float*)d_ws + 256;        // 128 f32

  int gE = (E + 255) / 256, gN = (n + 255) / 256;

  hipMemsetAsync(deg, 0, sizeof(int) * n, stream);
  k_deg_count<<<gE, 256, 0, stream>>>(col, deg, E);
  k_dinv<<<gN, 256, 0, stream>>>(deg, dinv, n);
  k_chunk_sum<<<nch, 256, 0, stream>>>(deg, csum, n);
  k_scan_serial<<<1, 1, 0, stream>>>(csum, cbase, nch);
  k_chunk_scan<<<nch, 256, 0, stream>>>(deg, cbase, off, n);
  k_copy_i32<<<gN, 256, 0, stream>>>(off, cursor, n);
  k_bucket<<<gE, 256, 0, stream>>>(row, col, cursor, srt, E);

  k_gemm<<<(n + 31) / 32, 256, 0, stream>>>(x, W1, bufA, n);
  k_agg<<<(n + 1) / 2, 256, 0, stream>>>(bufA, srt, off, dinv, b1, bufB, n, 1);
  k_gemm<<<(n + 31) / 32, 256, 0, stream>>>(bufB, W2, bufA, n);
  k_agg<<<(n + 1) / 2, 256, 0, stream>>>(bufA, srt, off, dinv, b2, bufB, n, 0);

  hipMemsetAsync(d_ws, 0, 256 * sizeof(float), stream);
  k_colmax<<<512, 256, 0, stream>>>(bufB, n, Mu);
  k_colsum<<<512, 256, 0, stream>>>(bufB, n, Mu, S);
  k_lse<<<1, 128, 0, stream>>>(Mu, S, L);
  k_final<<<(n * 32 + 255) / 256, 256, 0, stream>>>(bufB, L, out, n, B);
}

// Round 2
// 1074.384 us; speedup vs baseline: 1.4549x; 1.4549x over previous
//
#include <hip/hip_runtime.h>
#include <math.h>

#define DD 128

typedef unsigned int uint;

// ---------- bf16 helpers ----------

__device__ inline uint pack_bf16x2(float a, float b) {
  uint ua = __float_as_uint(a), ub = __float_as_uint(b);
  ua = (ua + 0x7fffu + ((ua >> 16) & 1u)) >> 16;
  ub = (ub + 0x7fffu + ((ub >> 16) & 1u)) & 0xffff0000u;
  return ua | ub;
}

// ---------- degree / CSR build ----------

__global__ __launch_bounds__(256) void k_deg_count(const int* __restrict__ col,
                                                   int* __restrict__ deg, int E) {
  int e = blockIdx.x * 256 + threadIdx.x;
  if (e < E) atomicAdd(&deg[col[e]], 1);
}

__global__ __launch_bounds__(256) void k_chunk_sum(const int* __restrict__ deg,
                                                   int* __restrict__ csum, int n) {
  __shared__ int s[256];
  int t = threadIdx.x, i = blockIdx.x * 256 + t;
  s[t] = (i < n) ? deg[i] : 0;
  __syncthreads();
  for (int o = 128; o > 0; o >>= 1) {
    if (t < o) s[t] += s[t + o];
    __syncthreads();
  }
  if (t == 0) csum[blockIdx.x] = s[0];
}

// one-block parallel scan over chunk sums (nch <= 1024)
__global__ __launch_bounds__(1024) void k_scan_block(const int* __restrict__ csum,
                                                     int* __restrict__ cbase, int nch) {
  __shared__ int s[1024];
  int t = threadIdx.x;
  int v = (t < nch) ? csum[t] : 0;
  s[t] = v;
  __syncthreads();
  for (int o = 1; o < 1024; o <<= 1) {
    int add = (t >= o) ? s[t - o] : 0;
    __syncthreads();
    s[t] += add;
    __syncthreads();
  }
  if (t < nch) cbase[t] = s[t] - v;  // exclusive
  if (t == nch - 1) cbase[nch] = s[t];
}

// per-chunk scan -> off[]; also emits cursor copy and dinv
__global__ __launch_bounds__(256) void k_chunk_scan(const int* __restrict__ deg,
                                                    const int* __restrict__ cbase,
                                                    int* __restrict__ off,
                                                    int* __restrict__ cursor,
                                                    float* __restrict__ dinv, int n) {
  __shared__ int s[256];
  int t = threadIdx.x, i = blockIdx.x * 256 + t;
  int v = (i < n) ? deg[i] : 0;
  s[t] = v;
  __syncthreads();
  for (int o = 1; o < 256; o <<= 1) {
    int add = (t >= o) ? s[t - o] : 0;
    __syncthreads();
    s[t] += add;
    __syncthreads();
  }
  int incl = s[t];
  int base = cbase[blockIdx.x];
  if (i < n) {
    int e = base + (incl - v);
    off[i] = e;
    cursor[i] = e;
    dinv[i] = rsqrtf(1.0f + (float)v);
  }
  if (i == n - 1) off[n] = base + incl;
}

__global__ __launch_bounds__(256) void k_bucket(const int* __restrict__ row,
                                                const int* __restrict__ col,
                                                int* __restrict__ cursor,
                                                int* __restrict__ srt, int E) {
  int e = blockIdx.x * 256 + threadIdx.x;
  if (e < E) {
    int d = col[e];
    int pos = atomicAdd(&cursor[d], 1);
    srt[pos] = row[e];
  }
}

// ---------- GEMM: msg[n,128](bf16) = dinv[n] * (X[n,128] @ W[128,128]) ----------
// 32 rows/block, 256 threads, each thread 4 rows x 4 cols. W staged in LDS
// in two k-halves (48KB static LDS -> 3 blocks/CU at 160KB).

__global__ __launch_bounds__(256, 2) void k_gemm(const float* __restrict__ X,
                                                 const float* __restrict__ W,
                                                 const float* __restrict__ dinv,
                                                 uint* __restrict__ msg, int nrows) {
  __shared__ float Ws[64 * 128];  // 32KB, one k-half
  __shared__ float Xs[32 * 128];  // 16KB
  int tid = threadIdx.x;
  int row0 = blockIdx.x * 32;

  for (int i = tid; i < 1024; i += 256) {
    int r = i >> 5, c = i & 31;
    int gr = row0 + r;
    float4 v = make_float4(0.f, 0.f, 0.f, 0.f);
    if (gr < nrows) v = ((const float4*)(X + (size_t)gr * DD))[c];
    ((float4*)Xs)[i] = v;
  }

  int cg = (tid & 31) * 4;
  int rbase = (tid >> 5) * 4;
  float acc[4][4];
#pragma unroll
  for (int a = 0; a < 4; a++)
#pragma unroll
    for (int b = 0; b < 4; b++) acc[a][b] = 0.f;

  for (int half = 0; half < 2; half++) {
    __syncthreads();
    for (int i = tid; i < 2048; i += 256)
      ((float4*)Ws)[i] = ((const float4*)(W + half * 64 * DD))[i];
    __syncthreads();
    int kbase = half * 64;
#pragma unroll 4
    for (int k = 0; k < 64; k += 4) {
      float4 xv[4];
#pragma unroll
      for (int rr = 0; rr < 4; rr++)
        xv[rr] = *(const float4*)&Xs[(rbase + rr) * DD + kbase + k];
#pragma unroll
      for (int kk = 0; kk < 4; kk++) {
        float4 wv = *(const float4*)&Ws[(k + kk) * DD + cg];
#pragma unroll
        for (int rr = 0; rr < 4; rr++) {
          float x = (kk == 0) ? xv[rr].x : (kk == 1) ? xv[rr].y : (kk == 2) ? xv[rr].z : xv[rr].w;
          acc[rr][0] += x * wv.x;
          acc[rr][1] += x * wv.y;
          acc[rr][2] += x * wv.z;
          acc[rr][3] += x * wv.w;
        }
      }
    }
  }

#pragma unroll
  for (int rr = 0; rr < 4; rr++) {
    int gr = row0 + rbase + rr;
    if (gr < nrows) {
      float di = dinv[gr];
      uint p0 = pack_bf16x2(acc[rr][0] * di, acc[rr][1] * di);
      uint p1 = pack_bf16x2(acc[rr][2] * di, acc[rr][3] * di);
      uint2* dst = (uint2*)(msg + (size_t)gr * 64 + (cg >> 1));
      *dst = make_uint2(p0, p1);
    }
  }
}

// ---------- aggregate: out[n,d] = f( dinv[n]*(sum_src msg[src,d] + msg[n,d]) + bias[d] )
// msg is bf16, pre-scaled by dinv[src]. One wave (64 lanes) per node; each lane
// owns 2 features (one uint). Edge indices: one coalesced load per 64-edge tile,
// broadcast via shfl; row gathers unrolled 8x for MLP.

__global__ __launch_bounds__(256) void k_agg(const uint* __restrict__ msg,
                                             const int* __restrict__ srt,
                                             const int* __restrict__ off,
                                             const float* __restrict__ dinv,
                                             const float* __restrict__ bias,
                                             float* __restrict__ out, int n, int relu) {
  int lane = threadIdx.x & 63;
  int node = blockIdx.x * 4 + (threadIdx.x >> 6);
  if (node >= n) return;
  int beg = off[node], end = off[node + 1];
  float a0 = 0.f, a1 = 0.f;
  for (int t = beg; t < end; t += 64) {
    int nt = end - t;
    if (nt > 64) nt = 64;
    int idx = srt[t + (lane < nt ? lane : nt - 1)];
    int k = 0;
    for (; k + 8 <= nt; k += 8) {
      uint r[8];
#pragma unroll
      for (int u = 0; u < 8; u++) {
        int s = __shfl(idx, k + u);
        r[u] = msg[(size_t)s * 64 + lane];
      }
#pragma unroll
      for (int u = 0; u < 8; u++) {
        a0 += __uint_as_float(r[u] << 16);
        a1 += __uint_as_float(r[u] & 0xffff0000u);
      }
    }
    for (; k < nt; k++) {
      int s = __shfl(idx, k);
      uint r = msg[(size_t)s * 64 + lane];
      a0 += __uint_as_float(r << 16);
      a1 += __uint_as_float(r & 0xffff0000u);
    }
  }
  // self-loop: + msg[node]  (agg = di * (sum + msg_self) + bias)
  uint rs = msg[(size_t)node * 64 + lane];
  a0 += __uint_as_float(rs << 16);
  a1 += __uint_as_float(rs & 0xffff0000u);
  float di = dinv[node];
  float2 bv = ((const float2*)bias)[lane];
  float v0 = di * a0 + bv.x;
  float v1 = di * a1 + bv.y;
  if (relu) { v0 = fmaxf(v0, 0.f); v1 = fmaxf(v1, 0.f); }
  ((float2*)(out + (size_t)node * DD))[lane] = make_float2(v0, v1);
}

// ---------- column logsumexp over node dim ----------

__device__ inline unsigned f2ord(float f) {
  unsigned b = __float_as_uint(f);
  return b ^ ((b >> 31) ? 0xFFFFFFFFu : 0x80000000u);
}
__device__ inline float ord2f(unsigned t) {
  unsigned b = t ^ ((t >> 31) ? 0x80000000u : 0xFFFFFFFFu);
  return __uint_as_float(b);
}

__global__ __launch_bounds__(256) void k_colmax(const float* __restrict__ h, int n,
                                                unsigned* __restrict__ Mu) {
  __shared__ float red[2][128];
  int d = threadIdx.x & 127, sub = threadIdx.x >> 7;
  float m = -3.4e38f;
  for (int r = blockIdx.x * 2 + sub; r < n; r += gridDim.x * 2)
    m = fmaxf(m, h[(size_t)r * DD + d]);
  red[sub][d] = m;
  __syncthreads();
  if (sub == 0) atomicMax(&Mu[d], f2ord(fmaxf(red[0][d], red[1][d])));
}

__global__ __launch_bounds__(256) void k_colsum(const float* __restrict__ h, int n,
                                                const unsigned* __restrict__ Mu,
                                                float* __restrict__ S) {
  __shared__ float red[2][128];
  int d = threadIdx.x & 127, sub = threadIdx.x >> 7;
  float M = ord2f(Mu[d]);
  float s = 0.f;
  for (int r = blockIdx.x * 2 + sub; r < n; r += gridDim.x * 2)
    s += expf(h[(size_t)r * DD + d] - M);
  red[sub][d] = s;
  __syncthreads();
  if (sub == 0) atomicAdd(&S[d], red[0][d] + red[1][d]);
}

__global__ void k_lse(const unsigned* __restrict__ Mu, const float* __restrict__ S,
                      float* __restrict__ L) {
  int d = threadIdx.x;
  L[d] = ord2f(Mu[d]) + logf(S[d]);
}

// ---------- final: out[b,n,d] = h2[n,d] - L[d], replicated over b ----------

__global__ __launch_bounds__(256) void k_final(const float* __restrict__ h,
                                               const float* __restrict__ L,
                                               float* __restrict__ out, int n, int B) {
  int idx = blockIdx.x * 256 + threadIdx.x;
  int nd4 = n * 32;
  if (idx >= nd4) return;
  int c4 = idx & 31;
  float4 hv = ((const float4*)h)[idx];
  float4 lv = ((const float4*)L)[c4];
  float4 r = make_float4(hv.x - lv.x, hv.y - lv.y, hv.z - lv.z, hv.w - lv.w);
  float4* o = (float4*)out;
  for (int b = 0; b < B; b++) o[(size_t)idx + (size_t)b * nd4] = r;
}

// ---------- launch ----------

extern "C" void kernel_launch(void* const* d_in, const int* in_sizes, int n_in,
                              void* d_out, int out_size, void* d_ws, size_t ws_size,
                              hipStream_t stream) {
  const float* x  = (const float*)d_in[0];
  const int*   ei = (const int*)d_in[1];
  const float* W1 = (const float*)d_in[3];
  const float* b1 = (const float*)d_in[4];
  const float* W2 = (const float*)d_in[5];
  const float* b2 = (const float*)d_in[6];
  // question_embeddings / Wq / bq cancel in log_softmax over the node axis.

  int n = in_sizes[0] / DD;
  int E = in_sizes[1] / 2;
  int B = out_size / (n * DD);
  const int* row = ei;
  const int* col = ei + E;

  float* out = (float*)d_out;
  size_t nd = (size_t)n * DD;
  // d_out as scratch: slab0 = h (f32), slab1 = h2 (f32, read in-place by
  // k_final), slab2 = srt (4E B) then msg (bf16, nd*2 B), slab3 = small arrays.
  // All scratch dead before k_final rewrites every output element.
  float* bufA = out;            // h after layer-1
  float* bufB = out + nd;       // h2 after layer-2
  int* srt = (int*)(out + 2 * nd);
  uint* msg = (uint*)((char*)(out + 2 * nd) + (size_t)4 * E);  // n*64 uints
  char* sm = (char*)(out + 3 * nd);
  int* deg = (int*)sm;        sm += sizeof(int) * n;
  float* dinv = (float*)sm;   sm += sizeof(float) * n;
  int* off = (int*)sm;        sm += sizeof(int) * (n + 1);
  int* cursor = (int*)sm;     sm += sizeof(int) * n;
  int nch = (n + 255) / 256;
  int* csum = (int*)sm;       sm += sizeof(int) * nch;
  int* cbase = (int*)sm;      sm += sizeof(int) * (nch + 1);

  unsigned* Mu = (unsigned*)d_ws;       // 128 u32
  float* S = (float*)d_ws + 128;        // 128 f32
  float* L = (float*)d_ws + 256;        // 128 f32

  int gE = (E + 255) / 256;

  hipMemsetAsync(deg, 0, sizeof(int) * n, stream);
  k_deg_count<<<gE, 256, 0, stream>>>(col, deg, E);
  k_chunk_sum<<<nch, 256, 0, stream>>>(deg, csum, n);
  k_scan_block<<<1, 1024, 0, stream>>>(csum, cbase, nch);
  k_chunk_scan<<<nch, 256, 0, stream>>>(deg, cbase, off, cursor, dinv, n);
  k_bucket<<<gE, 256, 0, stream>>>(row, col, cursor, srt, E);

  k_gemm<<<(n + 31) / 32, 256, 0, stream>>>(x, W1, dinv, msg, n);
  k_agg<<<(n + 3) / 4, 256, 0, stream>>>(msg, srt, off, dinv, b1, bufA, n, 1);
  k_gemm<<<(n + 31) / 32, 256, 0, stream>>>(bufA, W2, dinv, msg, n);
  k_agg<<<(n + 3) / 4, 256, 0, stream>>>(msg, srt, off, dinv, b2, bufB, n, 0);

  hipMemsetAsync(d_ws, 0, 256 * sizeof(float), stream);
  k_colmax<<<512, 256, 0, stream>>>(bufB, n, Mu);
  k_colsum<<<512, 256, 0, stream>>>(bufB, n, Mu, S);
  k_lse<<<1, 128, 0, stream>>>(Mu, S, L);
  k_final<<<(n * 32 + 255) / 256, 256, 0, stream>>>(bufB, L, out, n, B);
}

// Round 3
// 955.316 us; speedup vs baseline: 1.6362x; 1.1246x over previous
//
#include <hip/hip_runtime.h>
#include <math.h>

#define DD 128
#define CT 16384  // edges per coarse-pass block

typedef unsigned int uint;

// ---------- bf16 helpers ----------

__device__ inline uint pack_bf16x2(float a, float b) {
  uint ua = __float_as_uint(a), ub = __float_as_uint(b);
  ua = (ua + 0x7fffu + ((ua >> 16) & 1u)) >> 16;
  ub = (ub + 0x7fffu + ((ub >> 16) & 1u)) & 0xffff0000u;
  return ua | ub;
}

// ---------- degree / CSR build ----------

__global__ __launch_bounds__(256) void k_deg_count(const int* __restrict__ col,
                                                   int* __restrict__ deg, int E) {
  int e = blockIdx.x * 256 + threadIdx.x;
  if (e < E) atomicAdd(&deg[col[e]], 1);
}

__global__ __launch_bounds__(256) void k_chunk_sum(const int* __restrict__ deg,
                                                   int* __restrict__ csum, int n) {
  __shared__ int s[256];
  int t = threadIdx.x, i = blockIdx.x * 256 + t;
  s[t] = (i < n) ? deg[i] : 0;
  __syncthreads();
  for (int o = 128; o > 0; o >>= 1) {
    if (t < o) s[t] += s[t + o];
    __syncthreads();
  }
  if (t == 0) csum[blockIdx.x] = s[0];
}

// one-block parallel scan over chunk sums (nch <= 1024)
__global__ __launch_bounds__(1024) void k_scan_block(const int* __restrict__ csum,
                                                     int* __restrict__ cbase, int nch) {
  __shared__ int s[1024];
  int t = threadIdx.x;
  int v = (t < nch) ? csum[t] : 0;
  s[t] = v;
  __syncthreads();
  for (int o = 1; o < 1024; o <<= 1) {
    int add = (t >= o) ? s[t - o] : 0;
    __syncthreads();
    s[t] += add;
    __syncthreads();
  }
  if (t < nch) cbase[t] = s[t] - v;  // exclusive
  if (t == nch - 1) cbase[nch] = s[t];
}

// per-chunk scan -> off[]; also emits cursor copy and dinv
__global__ __launch_bounds__(256) void k_chunk_scan(const int* __restrict__ deg,
                                                    const int* __restrict__ cbase,
                                                    int* __restrict__ off,
                                                    int* __restrict__ cursor,
                                                    float* __restrict__ dinv, int n) {
  __shared__ int s[256];
  int t = threadIdx.x, i = blockIdx.x * 256 + t;
  int v = (i < n) ? deg[i] : 0;
  s[t] = v;
  __syncthreads();
  for (int o = 1; o < 256; o <<= 1) {
    int add = (t >= o) ? s[t - o] : 0;
    __syncthreads();
    s[t] += add;
    __syncthreads();
  }
  int incl = s[t];
  int base = cbase[blockIdx.x];
  if (i < n) {
    int e = base + (incl - v);
    off[i] = e;
    cursor[i] = e;
    dinv[i] = rsqrtf(1.0f + (float)v);
  }
  if (i == n - 1) off[n] = base + incl;
}

__global__ __launch_bounds__(256) void k_init_gcur(const int* __restrict__ off,
                                                   int* __restrict__ gcursor, int NB) {
  int b = blockIdx.x * 256 + threadIdx.x;
  if (b < NB) gcursor[b] = off[b * 256];
}

// coarse counting sort into 256-node buckets: entries written in per-block
// contiguous runs (~42 entries avg) -> write-combining friendly.
__global__ __launch_bounds__(256) void k_coarse(const int* __restrict__ row,
                                                const int* __restrict__ col,
                                                int* __restrict__ gcursor,
                                                uint2* __restrict__ coarse,
                                                int E, int NB) {
  __shared__ int hist[512];
  __shared__ int base[512];
  int tid = threadIdx.x;
  long e0 = (long)blockIdx.x * CT;
  int cnt = (int)min((long)CT, (long)E - e0);
  for (int i = tid; i < NB; i += 256) hist[i] = 0;
  __syncthreads();
  for (int i = tid; i < cnt; i += 256) atomicAdd(&hist[col[e0 + i] >> 8], 1);
  __syncthreads();
  for (int i = tid; i < NB; i += 256) {
    base[i] = atomicAdd(&gcursor[i], hist[i]);
    hist[i] = 0;  // reuse as local cursor (same thread owns index i)
  }
  __syncthreads();
  for (int i = tid; i < cnt; i += 256) {
    int c = col[e0 + i];
    int r = row[e0 + i];
    int b = c >> 8;
    int p = base[b] + atomicAdd(&hist[b], 1);
    coarse[p] = make_uint2((uint)r, (uint)c);
  }
}

// fine scatter: each block's 256 entries fall inside ~one 256-node bucket, so
// cursor atomics hit ~1KB and srt writes hit ~33KB (L2-resident) windows.
__global__ __launch_bounds__(256) void k_fine(const uint2* __restrict__ coarse,
                                              int* __restrict__ cursor,
                                              int* __restrict__ srt, int E) {
  int e = blockIdx.x * 256 + threadIdx.x;
  if (e < E) {
    uint2 v = coarse[e];
    int pos = atomicAdd(&cursor[v.y], 1);
    srt[pos] = (int)v.x;
  }
}

// ---------- GEMM: msg[n,128](bf16) = dinv[n] * (X[n,128] @ W[128,128]) ----------

__global__ __launch_bounds__(256, 2) void k_gemm(const float* __restrict__ X,
                                                 const float* __restrict__ W,
                                                 const float* __restrict__ dinv,
                                                 uint* __restrict__ msg, int nrows) {
  __shared__ float Ws[64 * 128];  // 32KB, one k-half
  __shared__ float Xs[32 * 128];  // 16KB
  int tid = threadIdx.x;
  int row0 = blockIdx.x * 32;

  for (int i = tid; i < 1024; i += 256) {
    int r = i >> 5, c = i & 31;
    int gr = row0 + r;
    float4 v = make_float4(0.f, 0.f, 0.f, 0.f);
    if (gr < nrows) v = ((const float4*)(X + (size_t)gr * DD))[c];
    ((float4*)Xs)[i] = v;
  }

  int cg = (tid & 31) * 4;
  int rbase = (tid >> 5) * 4;
  float acc[4][4];
#pragma unroll
  for (int a = 0; a < 4; a++)
#pragma unroll
    for (int b = 0; b < 4; b++) acc[a][b] = 0.f;

  for (int half = 0; half < 2; half++) {
    __syncthreads();
    for (int i = tid; i < 2048; i += 256)
      ((float4*)Ws)[i] = ((const float4*)(W + half * 64 * DD))[i];
    __syncthreads();
    int kbase = half * 64;
#pragma unroll 4
    for (int k = 0; k < 64; k += 4) {
      float4 xv[4];
#pragma unroll
      for (int rr = 0; rr < 4; rr++)
        xv[rr] = *(const float4*)&Xs[(rbase + rr) * DD + kbase + k];
#pragma unroll
      for (int kk = 0; kk < 4; kk++) {
        float4 wv = *(const float4*)&Ws[(k + kk) * DD + cg];
#pragma unroll
        for (int rr = 0; rr < 4; rr++) {
          float x = (kk == 0) ? xv[rr].x : (kk == 1) ? xv[rr].y : (kk == 2) ? xv[rr].z : xv[rr].w;
          acc[rr][0] += x * wv.x;
          acc[rr][1] += x * wv.y;
          acc[rr][2] += x * wv.z;
          acc[rr][3] += x * wv.w;
        }
      }
    }
  }

#pragma unroll
  for (int rr = 0; rr < 4; rr++) {
    int gr = row0 + rbase + rr;
    if (gr < nrows) {
      float di = dinv[gr];
      uint p0 = pack_bf16x2(acc[rr][0] * di, acc[rr][1] * di);
      uint p1 = pack_bf16x2(acc[rr][2] * di, acc[rr][3] * di);
      uint2* dst = (uint2*)(msg + (size_t)gr * 64 + (cg >> 1));
      *dst = make_uint2(p0, p1);
    }
  }
}

// ---------- aggregate: out[n,d] = f( dinv[n]*(sum_src msg[src,d] + msg[n,d]) + bias[d] )
// One wave per node, lane owns 2 features. 16 gathers in flight per wave;
// tail handled by a predicated 16-chunk (no serial remainder).

__global__ __launch_bounds__(256) void k_agg(const uint* __restrict__ msg,
                                             const int* __restrict__ srt,
                                             const int* __restrict__ off,
                                             const float* __restrict__ dinv,
                                             const float* __restrict__ bias,
                                             float* __restrict__ out, int n, int relu) {
  int lane = threadIdx.x & 63;
  int node = blockIdx.x * 4 + (threadIdx.x >> 6);
  if (node >= n) return;
  int beg = off[node], end = off[node + 1];
  float a0 = 0.f, a1 = 0.f;
  for (int t = beg; t < end; t += 64) {
    int nt = end - t;
    if (nt > 64) nt = 64;
    int idx = srt[t + (lane < nt ? lane : nt - 1)];
    int k = 0;
    for (; k + 16 <= nt; k += 16) {
      uint r[16];
#pragma unroll
      for (int u = 0; u < 16; u++) {
        int s = __shfl(idx, k + u);
        r[u] = msg[(size_t)s * 64 + lane];
      }
#pragma unroll
      for (int u = 0; u < 16; u++) {
        a0 += __uint_as_float(r[u] << 16);
        a1 += __uint_as_float(r[u] & 0xffff0000u);
      }
    }
    if (k < nt) {  // predicated tail: all gathers issued in parallel
      uint r[16];
#pragma unroll
      for (int u = 0; u < 16; u++) {
        int j = (k + u < nt) ? (k + u) : (nt - 1);
        int s = __shfl(idx, j);
        r[u] = msg[(size_t)s * 64 + lane];
      }
#pragma unroll
      for (int u = 0; u < 16; u++) {
        if (k + u < nt) {
          a0 += __uint_as_float(r[u] << 16);
          a1 += __uint_as_float(r[u] & 0xffff0000u);
        }
      }
    }
  }
  uint rs = msg[(size_t)node * 64 + lane];
  a0 += __uint_as_float(rs << 16);
  a1 += __uint_as_float(rs & 0xffff0000u);
  float di = dinv[node];
  float2 bv = ((const float2*)bias)[lane];
  float v0 = di * a0 + bv.x;
  float v1 = di * a1 + bv.y;
  if (relu) { v0 = fmaxf(v0, 0.f); v1 = fmaxf(v1, 0.f); }
  ((float2*)(out + (size_t)node * DD))[lane] = make_float2(v0, v1);
}

// ---------- column logsumexp over node dim ----------

__device__ inline unsigned f2ord(float f) {
  unsigned b = __float_as_uint(f);
  return b ^ ((b >> 31) ? 0xFFFFFFFFu : 0x80000000u);
}
__device__ inline float ord2f(unsigned t) {
  unsigned b = t ^ ((t >> 31) ? 0x80000000u : 0xFFFFFFFFu);
  return __uint_as_float(b);
}

__global__ __launch_bounds__(256) void k_colmax(const float* __restrict__ h, int n,
                                                unsigned* __restrict__ Mu) {
  __shared__ float red[2][128];
  int d = threadIdx.x & 127, sub = threadIdx.x >> 7;
  float m = -3.4e38f;
  for (int r = blockIdx.x * 2 + sub; r < n; r += gridDim.x * 2)
    m = fmaxf(m, h[(size_t)r * DD + d]);
  red[sub][d] = m;
  __syncthreads();
  if (sub == 0) atomicMax(&Mu[d], f2ord(fmaxf(red[0][d], red[1][d])));
}

__global__ __launch_bounds__(256) void k_colsum(const float* __restrict__ h, int n,
                                                const unsigned* __restrict__ Mu,
                                                float* __restrict__ S) {
  __shared__ float red[2][128];
  int d = threadIdx.x & 127, sub = threadIdx.x >> 7;
  float M = ord2f(Mu[d]);
  float s = 0.f;
  for (int r = blockIdx.x * 2 + sub; r < n; r += gridDim.x * 2)
    s += expf(h[(size_t)r * DD + d] - M);
  red[sub][d] = s;
  __syncthreads();
  if (sub == 0) atomicAdd(&S[d], red[0][d] + red[1][d]);
}

__global__ void k_lse(const unsigned* __restrict__ Mu, const float* __restrict__ S,
                      float* __restrict__ L) {
  int d = threadIdx.x;
  L[d] = ord2f(Mu[d]) + logf(S[d]);
}

// ---------- final: out[b,n,d] = h2[n,d] - L[d], replicated over b ----------

__global__ __launch_bounds__(256) void k_final(const float* __restrict__ h,
                                               const float* __restrict__ L,
                                               float* __restrict__ out, int n, int B) {
  int idx = blockIdx.x * 256 + threadIdx.x;
  int nd4 = n * 32;
  if (idx >= nd4) return;
  int c4 = idx & 31;
  float4 hv = ((const float4*)h)[idx];
  float4 lv = ((const float4*)L)[c4];
  float4 r = make_float4(hv.x - lv.x, hv.y - lv.y, hv.z - lv.z, hv.w - lv.w);
  float4* o = (float4*)out;
  for (int b = 0; b < B; b++) o[(size_t)idx + (size_t)b * nd4] = r;
}

// ---------- launch ----------

extern "C" void kernel_launch(void* const* d_in, const int* in_sizes, int n_in,
                              void* d_out, int out_size, void* d_ws, size_t ws_size,
                              hipStream_t stream) {
  const float* x  = (const float*)d_in[0];
  const int*   ei = (const int*)d_in[1];
  const float* W1 = (const float*)d_in[3];
  const float* b1 = (const float*)d_in[4];
  const float* W2 = (const float*)d_in[5];
  const float* b2 = (const float*)d_in[6];
  // question_embeddings / Wq / bq cancel in log_softmax over the node axis.

  int n = in_sizes[0] / DD;
  int E = in_sizes[1] / 2;
  int B = out_size / (n * DD);
  const int* row = ei;
  const int* col = ei + E;

  float* out = (float*)d_out;
  size_t nd = (size_t)n * DD;
  // d_out as scratch: slab0 = h (f32), slab1 = h2 (f32, read in-place by
  // k_final), slab2 = srt (4E) + [coarse (8E) overlapped with msg (2*nd)],
  // slab3 = small arrays. coarse is dead before k_gemm writes msg over it.
  float* bufA = out;            // h after layer-1
  float* bufB = out + nd;       // h2 after layer-2
  int* srt = (int*)(out + 2 * nd);
  uint2* coarse = (uint2*)((char*)srt + (size_t)4 * E);
  uint* msg = (uint*)coarse;    // n*64 uints, overwrites dead coarse
  char* sm = (char*)(out + 3 * nd);
  int* deg = (int*)sm;        sm += sizeof(int) * n;
  float* dinv = (float*)sm;   sm += sizeof(float) * n;
  int* off = (int*)sm;        sm += sizeof(int) * (n + 1);
  int* cursor = (int*)sm;     sm += sizeof(int) * n;
  int nch = (n + 255) / 256;
  int* csum = (int*)sm;       sm += sizeof(int) * nch;
  int* cbase = (int*)sm;      sm += sizeof(int) * (nch + 1);
  int NB = (n + 255) / 256;   // coarse buckets (256 nodes each)
  int* gcursor = (int*)sm;    sm += sizeof(int) * NB;

  unsigned* Mu = (unsigned*)d_ws;       // 128 u32
  float* S = (float*)d_ws + 128;        // 128 f32
  float* L = (float*)d_ws + 256;        // 128 f32

  int gE = (E + 255) / 256;

  hipMemsetAsync(deg, 0, sizeof(int) * n, stream);
  k_deg_count<<<gE, 256, 0, stream>>>(col, deg, E);
  k_chunk_sum<<<nch, 256, 0, stream>>>(deg, csum, n);
  k_scan_block<<<1, 1024, 0, stream>>>(csum, cbase, nch);
  k_chunk_scan<<<nch, 256, 0, stream>>>(deg, cbase, off, cursor, dinv, n);
  k_init_gcur<<<(NB + 255) / 256, 256, 0, stream>>>(off, gcursor, NB);
  k_coarse<<<(E + CT - 1) / CT, 256, 0, stream>>>(row, col, gcursor, coarse, E, NB);
  k_fine<<<gE, 256, 0, stream>>>(coarse, cursor, srt, E);

  k_gemm<<<(n + 31) / 32, 256, 0, stream>>>(x, W1, dinv, msg, n);
  k_agg<<<(n + 3) / 4, 256, 0, stream>>>(msg, srt, off, dinv, b1, bufA, n, 1);
  k_gemm<<<(n + 31) / 32, 256, 0, stream>>>(bufA, W2, dinv, msg, n);
  k_agg<<<(n + 3) / 4, 256, 0, stream>>>(msg, srt, off, dinv, b2, bufB, n, 0);

  hipMemsetAsync(d_ws, 0, 256 * sizeof(float), stream);
  k_colmax<<<512, 256, 0, stream>>>(bufB, n, Mu);
  k_colsum<<<512, 256, 0, stream>>>(bufB, n, Mu, S);
  k_lse<<<1, 128, 0, stream>>>(Mu, S, L);
  k_final<<<(n * 32 + 255) / 256, 256, 0, stream>>>(bufB, L, out, n, B);
}

// Round 4
// 782.565 us; speedup vs baseline: 1.9974x; 1.2208x over previous
//
#include <hip/hip_runtime.h>
#include <math.h>

#define DD 128
#define CT 16384  // edges per coarse-pass block

typedef unsigned int uint;

// ---------- bf16 helpers ----------

__device__ inline uint pack_bf16x2(float a, float b) {
  uint ua = __float_as_uint(a), ub = __float_as_uint(b);
  ua = (ua + 0x7fffu + ((ua >> 16) & 1u)) >> 16;
  ub = (ub + 0x7fffu + ((ub >> 16) & 1u)) & 0xffff0000u;
  return ua | ub;
}

// ---------- CSR build (two-level counting sort, no global per-node counters) ----------

// per-block LDS histogram of dst>>8 -> one global atomic per (block,bucket)
__global__ __launch_bounds__(256) void k_hist(const int* __restrict__ col,
                                              int* __restrict__ bucketCnt,
                                              int E, int NB) {
  __shared__ int hist[512];
  int tid = threadIdx.x;
  long e0 = (long)blockIdx.x * CT;
  int cnt = (int)min((long)CT, (long)E - e0);
  for (int i = tid; i < NB; i += 256) hist[i] = 0;
  __syncthreads();
  for (int i = tid; i < cnt; i += 256) atomicAdd(&hist[col[e0 + i] >> 8], 1);
  __syncthreads();
  for (int i = tid; i < NB; i += 256)
    if (hist[i]) atomicAdd(&bucketCnt[i], hist[i]);
}

// one-block exclusive scan over bucket counts (NB <= 1024); also inits cursors
__global__ __launch_bounds__(1024) void k_scan_block(const int* __restrict__ bucketCnt,
                                                     int* __restrict__ bucketBase,
                                                     int* __restrict__ gcursor, int NB) {
  __shared__ int s[1024];
  int t = threadIdx.x;
  int v = (t < NB) ? bucketCnt[t] : 0;
  s[t] = v;
  __syncthreads();
  for (int o = 1; o < 1024; o <<= 1) {
    int add = (t >= o) ? s[t - o] : 0;
    __syncthreads();
    s[t] += add;
    __syncthreads();
  }
  if (t < NB) {
    int e = s[t] - v;  // exclusive
    bucketBase[t] = e;
    gcursor[t] = e;
  }
  if (t == NB - 1) bucketBase[NB] = s[t];
}

// coarse counting sort into 256-node buckets; packed 4B entries (src<<8 | dstlow)
__global__ __launch_bounds__(256) void k_coarse(const int* __restrict__ row,
                                                const int* __restrict__ col,
                                                int* __restrict__ gcursor,
                                                uint* __restrict__ coarse,
                                                int E, int NB) {
  __shared__ int hist[512];
  __shared__ int base[512];
  int tid = threadIdx.x;
  long e0 = (long)blockIdx.x * CT;
  int cnt = (int)min((long)CT, (long)E - e0);
  for (int i = tid; i < NB; i += 256) hist[i] = 0;
  __syncthreads();
  for (int i = tid; i < cnt; i += 256) atomicAdd(&hist[col[e0 + i] >> 8], 1);
  __syncthreads();
  for (int i = tid; i < NB; i += 256) {
    base[i] = atomicAdd(&gcursor[i], hist[i]);
    hist[i] = 0;  // reuse as local cursor (same thread owns index i)
  }
  __syncthreads();
  for (int i = tid; i < cnt; i += 256) {
    int c = col[e0 + i];
    int r = row[e0 + i];
    int b = c >> 8;
    int p = base[b] + atomicAdd(&hist[b], 1);
    coarse[p] = ((uint)r << 8) | (uint)(c & 255);
  }
}

// one block per bucket: LDS histogram -> deg/dinv/off, then LDS-cursor scatter
// of srt within a ~33KB L2-resident window. Replaces the global degree count,
// three scan kernels, cursor array and global-atomic fine scatter.
__global__ __launch_bounds__(256) void k_finalize(const uint* __restrict__ coarse,
                                                  const int* __restrict__ bucketBase,
                                                  int* __restrict__ off,
                                                  float* __restrict__ dinv,
                                                  int* __restrict__ srt, int n, int NB) {
  __shared__ int hist[256];
  __shared__ int s[256];
  __shared__ int cur[256];
  int tid = threadIdx.x;
  int b = blockIdx.x;
  int base = bucketBase[b], endb = bucketBase[b + 1];
  int cnt = endb - base;
  int node0 = b << 8;
  hist[tid] = 0;
  __syncthreads();
  for (int i = tid; i < cnt; i += 256) atomicAdd(&hist[coarse[base + i] & 255u], 1);
  __syncthreads();
  int deg = hist[tid];
  s[tid] = deg;
  __syncthreads();
  for (int o = 1; o < 256; o <<= 1) {
    int add = (tid >= o) ? s[tid - o] : 0;
    __syncthreads();
    s[tid] += add;
    __syncthreads();
  }
  int excl = base + s[tid] - deg;
  int node = node0 + tid;
  if (node < n) {
    off[node] = excl;
    dinv[node] = rsqrtf(1.0f + (float)deg);
  }
  if (node == n - 1) off[n] = endb;
  cur[tid] = excl;
  __syncthreads();
  for (int i = tid; i < cnt; i += 256) {
    uint e = coarse[base + i];
    int pos = atomicAdd(&cur[e & 255u], 1);
    srt[pos] = (int)(e >> 8);
  }
}

// ---------- GEMM: msg[n,128](bf16) = dinv[n] * (X[n,128] @ W[128,128]) ----------

__global__ __launch_bounds__(256, 2) void k_gemm(const float* __restrict__ X,
                                                 const float* __restrict__ W,
                                                 const float* __restrict__ dinv,
                                                 uint* __restrict__ msg, int nrows) {
  __shared__ float Ws[64 * 128];  // 32KB, one k-half
  __shared__ float Xs[32 * 128];  // 16KB
  int tid = threadIdx.x;
  int row0 = blockIdx.x * 32;

  for (int i = tid; i < 1024; i += 256) {
    int r = i >> 5, c = i & 31;
    int gr = row0 + r;
    float4 v = make_float4(0.f, 0.f, 0.f, 0.f);
    if (gr < nrows) v = ((const float4*)(X + (size_t)gr * DD))[c];
    ((float4*)Xs)[i] = v;
  }

  int cg = (tid & 31) * 4;
  int rbase = (tid >> 5) * 4;
  float acc[4][4];
#pragma unroll
  for (int a = 0; a < 4; a++)
#pragma unroll
    for (int b = 0; b < 4; b++) acc[a][b] = 0.f;

  for (int half = 0; half < 2; half++) {
    __syncthreads();
    for (int i = tid; i < 2048; i += 256)
      ((float4*)Ws)[i] = ((const float4*)(W + half * 64 * DD))[i];
    __syncthreads();
    int kbase = half * 64;
#pragma unroll 4
    for (int k = 0; k < 64; k += 4) {
      float4 xv[4];
#pragma unroll
      for (int rr = 0; rr < 4; rr++)
        xv[rr] = *(const float4*)&Xs[(rbase + rr) * DD + kbase + k];
#pragma unroll
      for (int kk = 0; kk < 4; kk++) {
        float4 wv = *(const float4*)&Ws[(k + kk) * DD + cg];
#pragma unroll
        for (int rr = 0; rr < 4; rr++) {
          float x = (kk == 0) ? xv[rr].x : (kk == 1) ? xv[rr].y : (kk == 2) ? xv[rr].z : xv[rr].w;
          acc[rr][0] += x * wv.x;
          acc[rr][1] += x * wv.y;
          acc[rr][2] += x * wv.z;
          acc[rr][3] += x * wv.w;
        }
      }
    }
  }

#pragma unroll
  for (int rr = 0; rr < 4; rr++) {
    int gr = row0 + rbase + rr;
    if (gr < nrows) {
      float di = dinv[gr];
      uint p0 = pack_bf16x2(acc[rr][0] * di, acc[rr][1] * di);
      uint p1 = pack_bf16x2(acc[rr][2] * di, acc[rr][3] * di);
      uint2* dst = (uint2*)(msg + (size_t)gr * 64 + (cg >> 1));
      *dst = make_uint2(p0, p1);
    }
  }
}

// ---------- aggregate: out[n,d] = f( dinv[n]*(sum_src msg[src,d] + msg[n,d]) + bias[d] )

__global__ __launch_bounds__(256) void k_agg(const uint* __restrict__ msg,
                                             const int* __restrict__ srt,
                                             const int* __restrict__ off,
                                             const float* __restrict__ dinv,
                                             const float* __restrict__ bias,
                                             float* __restrict__ out, int n, int relu) {
  int lane = threadIdx.x & 63;
  int node = blockIdx.x * 4 + (threadIdx.x >> 6);
  if (node >= n) return;
  int beg = off[node], end = off[node + 1];
  float a0 = 0.f, a1 = 0.f;
  for (int t = beg; t < end; t += 64) {
    int nt = end - t;
    if (nt > 64) nt = 64;
    int idx = srt[t + (lane < nt ? lane : nt - 1)];
    int k = 0;
    for (; k + 16 <= nt; k += 16) {
      uint r[16];
#pragma unroll
      for (int u = 0; u < 16; u++) {
        int s = __shfl(idx, k + u);
        r[u] = msg[(size_t)s * 64 + lane];
      }
#pragma unroll
      for (int u = 0; u < 16; u++) {
        a0 += __uint_as_float(r[u] << 16);
        a1 += __uint_as_float(r[u] & 0xffff0000u);
      }
    }
    if (k < nt) {  // predicated tail: all gathers issued in parallel
      uint r[16];
#pragma unroll
      for (int u = 0; u < 16; u++) {
        int j = (k + u < nt) ? (k + u) : (nt - 1);
        int s = __shfl(idx, j);
        r[u] = msg[(size_t)s * 64 + lane];
      }
#pragma unroll
      for (int u = 0; u < 16; u++) {
        if (k + u < nt) {
          a0 += __uint_as_float(r[u] << 16);
          a1 += __uint_as_float(r[u] & 0xffff0000u);
        }
      }
    }
  }
  uint rs = msg[(size_t)node * 64 + lane];
  a0 += __uint_as_float(rs << 16);
  a1 += __uint_as_float(rs & 0xffff0000u);
  float di = dinv[node];
  float2 bv = ((const float2*)bias)[lane];
  float v0 = di * a0 + bv.x;
  float v1 = di * a1 + bv.y;
  if (relu) { v0 = fmaxf(v0, 0.f); v1 = fmaxf(v1, 0.f); }
  ((float2*)(out + (size_t)node * DD))[lane] = make_float2(v0, v1);
}

// ---------- column logsumexp over node dim ----------

__device__ inline unsigned f2ord(float f) {
  unsigned b = __float_as_uint(f);
  return b ^ ((b >> 31) ? 0xFFFFFFFFu : 0x80000000u);
}
__device__ inline float ord2f(unsigned t) {
  unsigned b = t ^ ((t >> 31) ? 0x80000000u : 0xFFFFFFFFu);
  return __uint_as_float(b);
}

__global__ __launch_bounds__(256) void k_colmax(const float* __restrict__ h, int n,
                                                unsigned* __restrict__ Mu) {
  __shared__ float red[2][128];
  int d = threadIdx.x & 127, sub = threadIdx.x >> 7;
  float m = -3.4e38f;
  for (int r = blockIdx.x * 2 + sub; r < n; r += gridDim.x * 2)
    m = fmaxf(m, h[(size_t)r * DD + d]);
  red[sub][d] = m;
  __syncthreads();
  if (sub == 0) atomicMax(&Mu[d], f2ord(fmaxf(red[0][d], red[1][d])));
}

__global__ __launch_bounds__(256) void k_colsum(const float* __restrict__ h, int n,
                                                const unsigned* __restrict__ Mu,
                                                float* __restrict__ S) {
  __shared__ float red[2][128];
  int d = threadIdx.x & 127, sub = threadIdx.x >> 7;
  float M = ord2f(Mu[d]);
  float s = 0.f;
  for (int r = blockIdx.x * 2 + sub; r < n; r += gridDim.x * 2)
    s += expf(h[(size_t)r * DD + d] - M);
  red[sub][d] = s;
  __syncthreads();
  if (sub == 0) atomicAdd(&S[d], red[0][d] + red[1][d]);
}

__global__ void k_lse(const unsigned* __restrict__ Mu, const float* __restrict__ S,
                      float* __restrict__ L) {
  int d = threadIdx.x;
  L[d] = ord2f(Mu[d]) + logf(S[d]);
}

// ---------- final: out[b,n,d] = h2[n,d] - L[d], replicated over b ----------

__global__ __launch_bounds__(256) void k_final(const float* __restrict__ h,
                                               const float* __restrict__ L,
                                               float* __restrict__ out, int n, int B) {
  int idx = blockIdx.x * 256 + threadIdx.x;
  int nd4 = n * 32;
  if (idx >= nd4) return;
  int c4 = idx & 31;
  float4 hv = ((const float4*)h)[idx];
  float4 lv = ((const float4*)L)[c4];
  float4 r = make_float4(hv.x - lv.x, hv.y - lv.y, hv.z - lv.z, hv.w - lv.w);
  float4* o = (float4*)out;
  for (int b = 0; b < B; b++) o[(size_t)idx + (size_t)b * nd4] = r;
}

// ---------- launch ----------

extern "C" void kernel_launch(void* const* d_in, const int* in_sizes, int n_in,
                              void* d_out, int out_size, void* d_ws, size_t ws_size,
                              hipStream_t stream) {
  const float* x  = (const float*)d_in[0];
  const int*   ei = (const int*)d_in[1];
  const float* W1 = (const float*)d_in[3];
  const float* b1 = (const float*)d_in[4];
  const float* W2 = (const float*)d_in[5];
  const float* b2 = (const float*)d_in[6];
  // question_embeddings / Wq / bq cancel in log_softmax over the node axis.

  int n = in_sizes[0] / DD;
  int E = in_sizes[1] / 2;
  int B = out_size / (n * DD);
  const int* row = ei;
  const int* col = ei + E;

  float* out = (float*)d_out;
  size_t nd = (size_t)n * DD;
  // d_out as scratch: slab0 = h (f32), slab1 = h2 (f32, read in-place by
  // k_final), slab2 = srt (4E) + [coarse (4E, packed) overlapped with msg
  // (2*nd)], slab3 = small arrays. coarse dead before k_gemm writes msg.
  float* bufA = out;            // h after layer-1
  float* bufB = out + nd;       // h2 after layer-2
  int* srt = (int*)(out + 2 * nd);
  uint* coarse = (uint*)((char*)srt + (size_t)4 * E);
  uint* msg = (uint*)coarse;    // n*64 uints, overwrites dead coarse
  char* sm = (char*)(out + 3 * nd);
  float* dinv = (float*)sm;   sm += sizeof(float) * n;
  int* off = (int*)sm;        sm += sizeof(int) * (n + 1);
  int NB = (n + 255) / 256;   // coarse buckets (256 nodes each)
  int* bucketCnt = (int*)sm;  sm += sizeof(int) * NB;
  int* bucketBase = (int*)sm; sm += sizeof(int) * (NB + 1);
  int* gcursor = (int*)sm;    sm += sizeof(int) * NB;

  unsigned* Mu = (unsigned*)d_ws;       // 128 u32
  float* S = (float*)d_ws + 128;        // 128 f32
  float* L = (float*)d_ws + 256;        // 128 f32

  int gC = (E + CT - 1) / CT;

  hipMemsetAsync(bucketCnt, 0, sizeof(int) * NB, stream);
  k_hist<<<gC, 256, 0, stream>>>(col, bucketCnt, E, NB);
  k_scan_block<<<1, 1024, 0, stream>>>(bucketCnt, bucketBase, gcursor, NB);
  k_coarse<<<gC, 256, 0, stream>>>(row, col, gcursor, coarse, E, NB);
  k_finalize<<<NB, 256, 0, stream>>>(coarse, bucketBase, off, dinv, srt, n, NB);

  k_gemm<<<(n + 31) / 32, 256, 0, stream>>>(x, W1, dinv, msg, n);
  k_agg<<<(n + 3) / 4, 256, 0, stream>>>(msg, srt, off, dinv, b1, bufA, n, 1);
  k_gemm<<<(n + 31) / 32, 256, 0, stream>>>(bufA, W2, dinv, msg, n);
  k_agg<<<(n + 3) / 4, 256, 0, stream>>>(msg, srt, off, dinv, b2, bufB, n, 0);

  hipMemsetAsync(d_ws, 0, 256 * sizeof(float), stream);
  k_colmax<<<512, 256, 0, stream>>>(bufB, n, Mu);
  k_colsum<<<512, 256, 0, stream>>>(bufB, n, Mu, S);
  k_lse<<<1, 128, 0, stream>>>(Mu, S, L);
  k_final<<<(n * 32 + 255) / 256, 256, 0, stream>>>(bufB, L, out, n, B);
}